// Round 4
// baseline (15.086 us; speedup 1.0000x reference)
//
#include <hip/hip_runtime.h>

// StatisticalSMA v4: out[b,t,c], t<96 — linear recurrence unrolled via
// compile-time chunk-start tables.  t split into 16 chunks of 6.
//
// chunk id q = (blockIdx&3)*4 + waveid  -- uniform (blockIdx bits are SGPR,
// waveid forced scalar via readfirstlane) -> uniform switch to run_chunk<Q>,
// whose chunk-start window (constexpr 5x5 fp32 table, derived in double)
// folds to FMA literals.  Zero coefficient memory traffic.
//
// Lanes: lane&15 = float4 column group, lane>>4 = batch-subgroup; block
// covers 4 batches x 4 chunks.  Grid 2048 blocks x 256 = 8192 waves =
// 32 waves/CU (4x the TLP of v3) to test whether the 14.5 us plateau is
// latency/drain (helps) or fixed dispatch overhead (no change).

#define SMA_B 2048
#define SMA_S 512
#define SMA_C 64
#define SMA_W 5
#define SMA_T 96
#define NCHUNK 16
#define TPC 6    // timesteps per chunk

struct ChunkWin { float c[NCHUNK][SMA_W][SMA_W]; };

// cw[q][i][j] = coefficient of initial window value j in window slot i after
// q*TPC recurrence steps (double precision, rounded once to fp32).
constexpr ChunkWin make_cw() {
    ChunkWin out{};
    double w[SMA_W][SMA_W] = {};
    for (int i = 0; i < SMA_W; ++i) w[i][i] = 1.0;
    for (int q = 0; q < NCHUNK; ++q) {
        for (int i = 0; i < SMA_W; ++i)
            for (int j = 0; j < SMA_W; ++j) out.c[q][i][j] = (float)w[i][j];
        for (int s = 0; s < TPC; ++s) {
            double f[SMA_W];
            for (int j = 0; j < SMA_W; ++j) {
                double a = 0.0;
                for (int i = 0; i < SMA_W; ++i) a += w[i][j];
                f[j] = a * 0.2;
            }
            for (int i = 0; i + 1 < SMA_W; ++i)
                for (int j = 0; j < SMA_W; ++j) w[i][j] = w[i + 1][j];
            for (int j = 0; j < SMA_W; ++j) w[SMA_W - 1][j] = f[j];
        }
    }
    return out;
}
constexpr ChunkWin kCW = make_cw();

template <int Q>
__device__ __forceinline__ void run_chunk(const float4 (&w)[SMA_W],
                                          float* __restrict__ op) {
    // chunk-start window: v[i] = sum_j kCW.c[Q][i][j] * w[j]; coefs are
    // compile-time literals, 0/1 entries fold away.
    float4 v[SMA_W];
    #pragma unroll
    for (int i = 0; i < SMA_W; ++i) {
        float ax = 0.f, ay = 0.f, az = 0.f, aw = 0.f;
        bool first = true;
        #pragma unroll
        for (int j = 0; j < SMA_W; ++j) {
            const float cj = kCW.c[Q][i][j];
            if (cj == 0.0f) continue;
            if (first) {
                ax = cj * w[j].x; ay = cj * w[j].y;
                az = cj * w[j].z; aw = cj * w[j].w;
                first = false;
            } else {
                ax += cj * w[j].x; ay += cj * w[j].y;
                az += cj * w[j].z; aw += cj * w[j].w;
            }
        }
        v[i] = make_float4(ax, ay, az, aw);
    }
    #pragma unroll
    for (int t = 0; t < TPC; ++t) {
        float4 f;
        f.x = (v[0].x + v[1].x + v[2].x + v[3].x + v[4].x) * 0.2f;
        f.y = (v[0].y + v[1].y + v[2].y + v[3].y + v[4].y) * 0.2f;
        f.z = (v[0].z + v[1].z + v[2].z + v[3].z + v[4].z) * 0.2f;
        f.w = (v[0].w + v[1].w + v[2].w + v[3].w + v[4].w) * 0.2f;
        *reinterpret_cast<float4*>(op + t * SMA_C) = f;
        v[0] = v[1]; v[1] = v[2]; v[2] = v[3]; v[3] = v[4]; v[4] = f;
    }
}

__global__ __launch_bounds__(256) void StatisticalSMA_kernel(
    const float* __restrict__ x, float* __restrict__ out) {
    const int lane = threadIdx.x & 63;
    const int wv   = __builtin_amdgcn_readfirstlane((int)(threadIdx.x >> 6));
    const int part = blockIdx.x & 3;    // which group of 4 chunks (SGPR)
    const int bg   = blockIdx.x >> 2;   // 4-batch group
    const int q    = part * 4 + wv;     // chunk id 0..15, wave-uniform
    const int colg = lane & 15;         // float4 column group
    const int bsub = lane >> 4;         // batch subgroup 0..3
    const int b    = bg * 4 + bsub;

    // initial window: x[b, S-W .. S-1, colg*4 .. +3]
    const float* xp = x + (size_t)b * (SMA_S * SMA_C)
                        + (SMA_S - SMA_W) * SMA_C + colg * 4;
    float4 w[SMA_W];
    #pragma unroll
    for (int i = 0; i < SMA_W; ++i)
        w[i] = *reinterpret_cast<const float4*>(xp + i * SMA_C);

    float* op = out + (size_t)b * (SMA_T * SMA_C)
                    + (size_t)(q * TPC) * SMA_C + colg * 4;
    switch (q) {
        case 0:  run_chunk<0>(w, op);  break;
        case 1:  run_chunk<1>(w, op);  break;
        case 2:  run_chunk<2>(w, op);  break;
        case 3:  run_chunk<3>(w, op);  break;
        case 4:  run_chunk<4>(w, op);  break;
        case 5:  run_chunk<5>(w, op);  break;
        case 6:  run_chunk<6>(w, op);  break;
        case 7:  run_chunk<7>(w, op);  break;
        case 8:  run_chunk<8>(w, op);  break;
        case 9:  run_chunk<9>(w, op);  break;
        case 10: run_chunk<10>(w, op); break;
        case 11: run_chunk<11>(w, op); break;
        case 12: run_chunk<12>(w, op); break;
        case 13: run_chunk<13>(w, op); break;
        case 14: run_chunk<14>(w, op); break;
        default: run_chunk<15>(w, op); break;
    }
}

extern "C" void kernel_launch(void* const* d_in, const int* in_sizes, int n_in,
                              void* d_out, int out_size, void* d_ws, size_t ws_size,
                              hipStream_t stream) {
    const float* x = (const float*)d_in[0];
    float* out = (float*)d_out;
    StatisticalSMA_kernel<<<SMA_B, 256, 0, stream>>>(x, out);
}